// Round 22
// baseline (80.558 us; speedup 1.0000x reference)
//
#include <hip/hip_runtime.h>
#include <math.h>

typedef short  short8 __attribute__((ext_vector_type(8)));
typedef float  f32x4  __attribute__((ext_vector_type(4)));
typedef float  f32x16 __attribute__((ext_vector_type(16)));

#define ZQ_ELEMS 4194304    // 16*64*64*64
#define KC       1024
#define EPS_HALF 0.005f

// Output layout (fp32, concat): [0,4194304) z_q_st ; [4194304] vq_loss ;
// [4194305, 4259841) indices (as float)
//
// ws layout (bytes):
//   [0,262144)           ushort epack[1024][128]   per code: hi[64] | lo[64]
//   [262144,266240)      float  enorm_s[1024]      (-0.5 * ||e||^2)
//   [266240,266244)      int    risky_cnt
//   [270336,524288)      int    risky[63488]

__device__ inline unsigned short bf16_rne(float f) {
    union { float fv; unsigned u; } a; a.fv = f;
    unsigned r = a.u + 0x7FFFu + ((a.u >> 16) & 1u);
    return (unsigned short)(r >> 16);
}
__device__ inline float bf16_to_f(unsigned short h) {
    union { unsigned u; float fv; } a; a.u = ((unsigned)h) << 16;
    return a.fv;
}
// packed (score, 1023-code) ordered compare via f64 max; near-ties are all
// rescored exactly, so tie direction here is irrelevant.
__device__ inline double dpack(float hi, unsigned lo) {
    return __hiloint2double(__float_as_int(hi), (int)lo);
}
__device__ inline float dhi(double d) { return __int_as_float(__double2hiint(d)); }
__device__ inline unsigned dlo(double d) { return (unsigned)__double2loint(d); }

__global__ __launch_bounds__(256) void vq_prep(const float* __restrict__ emb,
        unsigned short* __restrict__ epack, float* __restrict__ enorm_s,
        int* __restrict__ risky_cnt, float* __restrict__ out) {
    const int k = blockIdx.x * 256 + threadIdx.x;   // grid 4
    if (k == 0) { *risky_cnt = 0; out[ZQ_ELEMS] = 0.f; }
    const float4* e4 = (const float4*)(emb + k * 64);
    float s = 0.f;
#pragma unroll
    for (int j = 0; j < 16; ++j) {
        float4 v = e4[j];
        float vv[4] = {v.x, v.y, v.z, v.w};
        ushort4 hv, lv;
        unsigned short h[4], l[4];
#pragma unroll
        for (int t = 0; t < 4; ++t) {
            s = fmaf(vv[t], vv[t], s);
            h[t] = bf16_rne(vv[t]);
            l[t] = bf16_rne(vv[t] - bf16_to_f(h[t]));
        }
        hv.x = h[0]; hv.y = h[1]; hv.z = h[2]; hv.w = h[3];
        lv.x = l[0]; lv.y = l[1]; lv.z = l[2]; lv.w = l[3];
        *(ushort4*)(epack + k * 128 + j * 4)      = hv;
        *(ushort4*)(epack + k * 128 + 64 + j * 4) = lv;
    }
    enorm_s[k] = -0.5f * s;
}

// Block-local full pipeline, 32x32x16 MFMA: block = 64 px, 4 waves; each wave
// owns 32 codes/pass x 8 passes (4w x 32c x 8 = 1024). Per pass: 2 px-tiles of
// 32. Lane holds 16 codes of ITS px column -> in-register argmin tree + one
// shfl_xor(32) at the end. Gather + z_q + loss inline. Grid 1024.
__global__ __launch_bounds__(256) void vq_scan(const float* __restrict__ z_e,
        const unsigned short* __restrict__ epack, const float* __restrict__ enorm_s,
        const float* __restrict__ emb, float* __restrict__ out,
        int* __restrict__ risky_cnt, int* __restrict__ risky) {
    const int tid  = threadIdx.x;
    const int lane = tid & 63;
    const int px   = lane & 31;
    const int hi32 = lane >> 5;               // 0/1: k-subgroup & code +4 offset
    const int wv   = __builtin_amdgcn_readfirstlane(tid >> 6);
    const int pblk = blockIdx.x * 64;

    __shared__ __align__(16) char smem[19456];
    unsigned short* afrag = (unsigned short*)smem;          // [64 px][hi64|lo64]
    double* mrgB = (double*)(smem + 16384);                 // [4][64]
    float*  mrgS = (float*)(smem + 18432);                  // [4][64]
    float (*zq)[65] = (float (*)[65])smem;                  // gather alias (16.6KB)
    __shared__ int   sidx[64];
    __shared__ float sred[4];

    // ---- stage + convert 64 pixels into LDS (once; no redundancy)
    {
        const int lp = tid & 63;
        const int pg = pblk + lp;
        const float* zb = z_e + (pg >> 12) * 262144 + (pg & 4095);
        const int sx = (lp & 7) << 3;
#pragma unroll
        for (int s8 = 0; s8 < 2; ++s8) {
            const int d0 = wv * 16 + s8 * 8;
            short8 H, L;
#pragma unroll
            for (int j = 0; j < 8; ++j) {
                float v = zb[(d0 + j) * 4096];
                unsigned short h = bf16_rne(v);
                H[j] = (short)h;
                L[j] = (short)bf16_rne(v - bf16_to_f(h));
            }
            const int sw = d0 ^ sx;                // 16B-granular XOR swizzle
            *(short8*)&afrag[lp * 128 + sw]      = H;
            *(short8*)&afrag[lp * 128 + 64 + sw] = L;
        }
    }
    __syncthreads();

    const int half8 = hi32 * 8;                // k offset within each 16-chunk
    const f32x16 zero16 = {0.f,0.f,0.f,0.f,0.f,0.f,0.f,0.f,
                           0.f,0.f,0.f,0.f,0.f,0.f,0.f,0.f};

    double Brun[2];
    float  Srun[2];
#pragma unroll
    for (int t = 0; t < 2; ++t) { Brun[t] = dpack(-INFINITY, 0u); Srun[t] = -INFINITY; }

#pragma unroll 1
    for (int pass = 0; pass < 8; ++pass) {
        const int cbase = pass * 128 + wv * 32;
        // ---- A fragments: lane's code row = cbase + px, k = chunk*16 + half8 + j
        const unsigned short* pe = epack + (cbase + px) * 128 + half8;
        const short8 ah0 = *(const short8*)(pe);
        const short8 ah1 = *(const short8*)(pe + 16);
        const short8 ah2 = *(const short8*)(pe + 32);
        const short8 ah3 = *(const short8*)(pe + 48);
        const short8 al0 = *(const short8*)(pe + 64);
        const short8 al1 = *(const short8*)(pe + 80);
        const short8 al2 = *(const short8*)(pe + 96);
        const short8 al3 = *(const short8*)(pe + 112);
        // ---- enorm for the lane's 16 C/D rows: codes cbase+4*hi32+{0..3,8..11,16..19,24..27}
        f32x16 enf;
        {
            const float4 e0 = *(const float4*)(enorm_s + cbase + 4 * hi32);
            const float4 e1 = *(const float4*)(enorm_s + cbase + 4 * hi32 + 8);
            const float4 e2 = *(const float4*)(enorm_s + cbase + 4 * hi32 + 16);
            const float4 e3 = *(const float4*)(enorm_s + cbase + 4 * hi32 + 24);
            enf[0]=e0.x; enf[1]=e0.y; enf[2]=e0.z; enf[3]=e0.w;
            enf[4]=e1.x; enf[5]=e1.y; enf[6]=e1.z; enf[7]=e1.w;
            enf[8]=e2.x; enf[9]=e2.y; enf[10]=e2.z; enf[11]=e2.w;
            enf[12]=e3.x; enf[13]=e3.y; enf[14]=e3.z; enf[15]=e3.w;
        }
        const int K1 = 1023 - cbase - 4 * hi32;

#pragma unroll
        for (int tile = 0; tile < 2; ++tile) {
            const int lpx = tile * 32 + px;
            const int sxp = (lpx & 7) << 3;
            const unsigned short* bp = &afrag[lpx * 128];
            const short8 bh0 = *(const short8*)&bp[(0  + half8) ^ sxp];
            const short8 bh1 = *(const short8*)&bp[(16 + half8) ^ sxp];
            const short8 bh2 = *(const short8*)&bp[(32 + half8) ^ sxp];
            const short8 bh3 = *(const short8*)&bp[(48 + half8) ^ sxp];
            const short8 bl0 = *(const short8*)&bp[64 + ((0  + half8) ^ sxp)];
            const short8 bl1 = *(const short8*)&bp[64 + ((16 + half8) ^ sxp)];
            const short8 bl2 = *(const short8*)&bp[64 + ((32 + half8) ^ sxp)];
            const short8 bl3 = *(const short8*)&bp[64 + ((48 + half8) ^ sxp)];

            // two independent 6-chains: aA = chunks 0,1; aB = chunks 2,3
            f32x16 aA = enf, aB = zero16;
            aA = __builtin_amdgcn_mfma_f32_32x32x16_bf16(ah0, bh0, aA, 0, 0, 0);
            aB = __builtin_amdgcn_mfma_f32_32x32x16_bf16(ah2, bh2, aB, 0, 0, 0);
            aA = __builtin_amdgcn_mfma_f32_32x32x16_bf16(al0, bh0, aA, 0, 0, 0);
            aB = __builtin_amdgcn_mfma_f32_32x32x16_bf16(al2, bh2, aB, 0, 0, 0);
            aA = __builtin_amdgcn_mfma_f32_32x32x16_bf16(ah0, bl0, aA, 0, 0, 0);
            aB = __builtin_amdgcn_mfma_f32_32x32x16_bf16(ah2, bl2, aB, 0, 0, 0);
            aA = __builtin_amdgcn_mfma_f32_32x32x16_bf16(ah1, bh1, aA, 0, 0, 0);
            aB = __builtin_amdgcn_mfma_f32_32x32x16_bf16(ah3, bh3, aB, 0, 0, 0);
            aA = __builtin_amdgcn_mfma_f32_32x32x16_bf16(al1, bh1, aA, 0, 0, 0);
            aB = __builtin_amdgcn_mfma_f32_32x32x16_bf16(al3, bh3, aB, 0, 0, 0);
            aA = __builtin_amdgcn_mfma_f32_32x32x16_bf16(ah1, bl1, aA, 0, 0, 0);
            aB = __builtin_amdgcn_mfma_f32_32x32x16_bf16(ah3, bl3, aB, 0, 0, 0);

            // 16 packed candidates (row reg -> code K1-(reg&3)-8*(reg>>2))
            double cand[16];
#pragma unroll
            for (int reg = 0; reg < 16; ++reg)
                cand[reg] = dpack(aA[reg] + aB[reg],
                                  (unsigned)(K1 - (reg & 3) - 8 * (reg >> 2)));
            // in-register binary tree (B,S) reduce over 16
            double tB[8]; float tS[8];
#pragma unroll
            for (int i = 0; i < 8; ++i) {
                tB[i] = fmax(cand[2 * i], cand[2 * i + 1]);
                tS[i] = fminf(dhi(cand[2 * i]), dhi(cand[2 * i + 1]));
            }
#pragma unroll
            for (int lvl = 4; lvl >= 1; lvl >>= 1) {
#pragma unroll
                for (int i = 0; i < lvl; ++i) {
                    tS[i] = __builtin_amdgcn_fmed3f(dhi(tB[i]), dhi(tB[i + lvl]),
                                                    fmaxf(tS[i], tS[i + lvl]));
                    tB[i] = fmax(tB[i], tB[i + lvl]);
                }
            }
            Srun[tile] = __builtin_amdgcn_fmed3f(dhi(Brun[tile]), dhi(tB[0]),
                                                 fmaxf(Srun[tile], tS[0]));
            Brun[tile] = fmax(Brun[tile], tB[0]);
        }
    }

    // ---- merge code-halves across lane^32 (each tile), select own px slot
#pragma unroll
    for (int t = 0; t < 2; ++t) {
        const double ob = __shfl_xor(Brun[t], 32, 64);
        const float  o2 = __shfl_xor(Srun[t], 32, 64);
        Srun[t] = __builtin_amdgcn_fmed3f(dhi(Brun[t]), dhi(ob), fmaxf(Srun[t], o2));
        Brun[t] = fmax(Brun[t], ob);
    }
    __syncthreads();              // afrag reads complete
    mrgB[wv * 64 + lane] = hi32 ? Brun[1] : Brun[0];   // lane<32: px tile0; else tile1
    mrgS[wv * 64 + lane] = hi32 ? Srun[1] : Srun[0];
    __syncthreads();

    // ---- wave 0: merge the 4 waves' results -> idx + risky compact
    if (tid < 64) {
        double B = mrgB[tid];
        float  S = mrgS[tid];
#pragma unroll
        for (int w = 1; w < 4; ++w) {
            const double ob = mrgB[w * 64 + tid];
            const float  o2 = mrgS[w * 64 + tid];
            S = __builtin_amdgcn_fmed3f(dhi(B), dhi(ob), fmaxf(S, o2));
            B = fmax(B, ob);
        }
        const int idx = 1023 - (int)dlo(B);
        sidx[tid] = idx;
        out[ZQ_ELEMS + 1 + pblk + tid] = (float)idx;
        const bool risk = (dhi(B) - S < EPS_HALF);
        const unsigned long long m = __ballot(risk);
        int base = 0;
        if (lane == 0 && m) base = atomicAdd(risky_cnt, __popcll(m));
        base = __shfl(base, 0, 64);
        if (risk) risky[base + __popcll(m & ((1ull << lane) - 1ull))] = pblk + tid;
    }
    __syncthreads();

    // ---- gather: coalesced codebook-row reads (zq aliases afrag+mrgB)
#pragma unroll
    for (int i = 0; i < 16; ++i) {
        const int p = wv * 16 + i;
        const int k = sidx[p];                 // LDS read, wave-uniform broadcast
        zq[p][lane] = emb[k * 64 + lane];
    }
    __syncthreads();

    // ---- (B,D,H,W)-major float4 writes + fused loss
    const int batch = pblk >> 12;
    const int hw0   = pblk & 4095;
    const int p4 = (tid & 15) * 4;
    const float* zeb = z_e + batch * 262144 + hw0;
    float* ob = out + batch * 262144 + hw0;
    float ss = 0.f;
#pragma unroll
    for (int it = 0; it < 4; ++it) {
        const int d = (tid >> 4) + it * 16;
        float4 q;
        q.x = zq[p4 + 0][d]; q.y = zq[p4 + 1][d];
        q.z = zq[p4 + 2][d]; q.w = zq[p4 + 3][d];
        const float4 z = *(const float4*)(zeb + d * 4096 + p4);
        *(float4*)(ob + d * 4096 + p4) = q;
        const float e0 = q.x - z.x, e1 = q.y - z.y, e2 = q.z - z.z, e3 = q.w - z.w;
        ss += e0 * e0 + e1 * e1 + e2 * e2 + e3 * e3;
    }
    for (int off = 32; off; off >>= 1) ss += __shfl_down(ss, off, 64);
    if (lane == 0) sred[wv] = ss;
    __syncthreads();
    if (tid == 0)
        atomicAdd(out + ZQ_ELEMS,
                  ((sred[0] + sred[1]) + (sred[2] + sred[3])) * (1.25f / (float)ZQ_ELEMS));
}

// Exact fp64 fixup (r18 proven version): wave per flagged pixel; emb staged
// per 64-code tile into padded LDS. Patches idx + z_q row + loss delta.
// Grid 512; idle blocks exit.
__global__ __launch_bounds__(256) void vq_fix(const float* __restrict__ z_e,
        const float* __restrict__ emb, float* __restrict__ out,
        const int* __restrict__ cnt, const int* __restrict__ list) {
    const int n = *cnt;
    if ((int)blockIdx.x * 4 >= n) return;
    __shared__ float etile[64][65];
    const int tid  = threadIdx.x;
    const int lane = tid & 63;
    const int wv   = __builtin_amdgcn_readfirstlane(tid >> 6);

    for (int base = blockIdx.x * 4; base < n; base += gridDim.x * 4) {
        const int item = base + wv;
        const bool active = item < n;
        int pix = 0, oldk = 0;
        float f[64];
        if (active) {
            pix = list[item];
            const float* zb = z_e + (pix >> 12) * 262144 + (pix & 4095);
#pragma unroll
            for (int d = 0; d < 64; ++d) f[d] = zb[d * 4096];
            oldk = (int)out[ZQ_ELEMS + 1 + pix];
        }
        double best = INFINITY; int bk = KC;
        double dold = 0.0;
        for (int j = 0; j < 16; ++j) {
            __syncthreads();
#pragma unroll
            for (int i = 0; i < 16; ++i) {
                const int idx = i * 256 + tid;
                etile[idx >> 6][idx & 63] = emb[j * 4096 + idx];
            }
            __syncthreads();
            if (active) {
                const int k = j * 64 + lane;
                double a0 = 0.0, a1 = 0.0;
#pragma unroll
                for (int d = 0; d < 64; d += 2) {
                    const double d0 = (double)f[d]     - (double)etile[lane][d];
                    const double d1 = (double)f[d + 1] - (double)etile[lane][d + 1];
                    a0 = fma(d0, d0, a0);
                    a1 = fma(d1, d1, a1);
                }
                const double acc = a0 + a1;
                if (acc < best || (acc == best && k < bk)) { best = acc; bk = k; }
                if (k == oldk) dold = acc;
            }
        }
        if (active) {
            for (int off = 32; off; off >>= 1) {
                const double ov = __shfl_down(best, off, 64);
                const int    oi = __shfl_down(bk, off, 64);
                if (ov < best || (ov == best && oi < bk)) { best = ov; bk = oi; }
            }
            for (int off = 32; off; off >>= 1) dold += __shfl_down(dold, off, 64);
            bk   = __shfl(bk, 0, 64);
            best = __shfl(best, 0, 64);
            dold = __shfl(dold, 0, 64);
            if (bk != oldk) {
                if (lane == 0) out[ZQ_ELEMS + 1 + pix] = (float)bk;
                out[(pix >> 12) * 262144 + (pix & 4095) + lane * 4096] = emb[bk * 64 + lane];
                if (lane == 0)
                    atomicAdd(out + ZQ_ELEMS,
                              (float)((best - dold) * (1.25 / (double)ZQ_ELEMS)));
            }
        }
    }
}

extern "C" void kernel_launch(void* const* d_in, const int* in_sizes, int n_in,
                              void* d_out, int out_size, void* d_ws, size_t ws_size,
                              hipStream_t stream) {
    const float* z_e = (const float*)d_in[0];
    const float* emb = (const float*)d_in[1];
    float* out = (float*)d_out;
    char* ws = (char*)d_ws;
    unsigned short* epack = (unsigned short*)ws;
    float*  enorm_s   = (float*)(ws + 262144);
    int*    risky_cnt = (int*)(ws + 266240);
    int*    risky     = (int*)(ws + 270336);

    vq_prep<<<4, 256, 0, stream>>>(emb, epack, enorm_s, risky_cnt, out);
    vq_scan<<<1024, 256, 0, stream>>>(z_e, epack, enorm_s, emb, out, risky_cnt, risky);
    vq_fix<<<512, 256, 0, stream>>>(z_e, emb, out, risky_cnt, risky);
}

// Round 23
// 80.540 us; speedup vs baseline: 1.0002x; 1.0002x over previous
//
#include <hip/hip_runtime.h>
#include <math.h>

typedef short  short8 __attribute__((ext_vector_type(8)));
typedef float  f32x4  __attribute__((ext_vector_type(4)));
typedef float  f32x16 __attribute__((ext_vector_type(16)));

#define ZQ_ELEMS 4194304    // 16*64*64*64
#define KC       1024
#define EPS_HALF 0.005f

// Output layout (fp32, concat): [0,4194304) z_q_st ; [4194304] vq_loss ;
// [4194305, 4259841) indices (as float)
//
// ws layout (bytes):
//   [0,262144)           ushort epack[1024][128]   per code: hi[64] | lo[64]
//   [262144,266240)      float  enorm_s[1024]      (-0.5 * ||e||^2)
//   [266240,266244)      int    risky_cnt
//   [270336,524288)      int    risky[63488]

__device__ inline unsigned short bf16_rne(float f) {
    union { float fv; unsigned u; } a; a.fv = f;
    unsigned r = a.u + 0x7FFFu + ((a.u >> 16) & 1u);
    return (unsigned short)(r >> 16);
}
__device__ inline float bf16_to_f(unsigned short h) {
    union { unsigned u; float fv; } a; a.u = ((unsigned)h) << 16;
    return a.fv;
}
// packed (score, 1023-code) ordered compare via f64 max; near-ties are all
// rescored exactly, so tie direction here is irrelevant.
__device__ inline double dpack(float hi, unsigned lo) {
    return __hiloint2double(__float_as_int(hi), (int)lo);
}
__device__ inline float dhi(double d) { return __int_as_float(__double2hiint(d)); }
__device__ inline unsigned dlo(double d) { return (unsigned)__double2loint(d); }

__global__ __launch_bounds__(256) void vq_prep(const float* __restrict__ emb,
        unsigned short* __restrict__ epack, float* __restrict__ enorm_s,
        int* __restrict__ risky_cnt, float* __restrict__ out) {
    const int k = blockIdx.x * 256 + threadIdx.x;   // grid 4
    if (k == 0) { *risky_cnt = 0; out[ZQ_ELEMS] = 0.f; }
    const float4* e4 = (const float4*)(emb + k * 64);
    float s = 0.f;
#pragma unroll
    for (int j = 0; j < 16; ++j) {
        float4 v = e4[j];
        float vv[4] = {v.x, v.y, v.z, v.w};
        ushort4 hv, lv;
        unsigned short h[4], l[4];
#pragma unroll
        for (int t = 0; t < 4; ++t) {
            s = fmaf(vv[t], vv[t], s);
            h[t] = bf16_rne(vv[t]);
            l[t] = bf16_rne(vv[t] - bf16_to_f(h[t]));
        }
        hv.x = h[0]; hv.y = h[1]; hv.z = h[2]; hv.w = h[3];
        lv.x = l[0]; lv.y = l[1]; lv.z = l[2]; lv.w = l[3];
        *(ushort4*)(epack + k * 128 + j * 4)      = hv;
        *(ushort4*)(epack + k * 128 + 64 + j * 4) = lv;
    }
    enorm_s[k] = -0.5f * s;
}

// Block-local full pipeline, 32x32x16 MFMA: block = 64 px, 4 waves; each wave
// owns 32 codes/pass x 8 passes (4w x 32c x 8 = 1024). Per pass: 2 px-tiles of
// 32. Lane holds 16 codes of ITS px column -> in-register argmin tree + one
// shfl_xor(32) at the end. Gather + z_q + loss inline. Grid 1024.
__global__ __launch_bounds__(256) void vq_scan(const float* __restrict__ z_e,
        const unsigned short* __restrict__ epack, const float* __restrict__ enorm_s,
        const float* __restrict__ emb, float* __restrict__ out,
        int* __restrict__ risky_cnt, int* __restrict__ risky) {
    const int tid  = threadIdx.x;
    const int lane = tid & 63;
    const int px   = lane & 31;
    const int hi32 = lane >> 5;               // 0/1: k-subgroup & code +4 offset
    const int wv   = __builtin_amdgcn_readfirstlane(tid >> 6);
    const int pblk = blockIdx.x * 64;

    __shared__ __align__(16) char smem[19456];
    unsigned short* afrag = (unsigned short*)smem;          // [64 px][hi64|lo64]
    double* mrgB = (double*)(smem + 16384);                 // [4][64]
    float*  mrgS = (float*)(smem + 18432);                  // [4][64]
    float (*zq)[65] = (float (*)[65])smem;                  // gather alias (16.6KB)
    __shared__ int   sidx[64];
    __shared__ float sred[4];

    // ---- stage + convert 64 pixels into LDS (once; no redundancy)
    {
        const int lp = tid & 63;
        const int pg = pblk + lp;
        const float* zb = z_e + (pg >> 12) * 262144 + (pg & 4095);
        const int sx = (lp & 7) << 3;
#pragma unroll
        for (int s8 = 0; s8 < 2; ++s8) {
            const int d0 = wv * 16 + s8 * 8;
            short8 H, L;
#pragma unroll
            for (int j = 0; j < 8; ++j) {
                float v = zb[(d0 + j) * 4096];
                unsigned short h = bf16_rne(v);
                H[j] = (short)h;
                L[j] = (short)bf16_rne(v - bf16_to_f(h));
            }
            const int sw = d0 ^ sx;                // 16B-granular XOR swizzle
            *(short8*)&afrag[lp * 128 + sw]      = H;
            *(short8*)&afrag[lp * 128 + 64 + sw] = L;
        }
    }
    __syncthreads();

    const int half8 = hi32 * 8;                // k offset within each 16-chunk
    const f32x16 zero16 = {0.f,0.f,0.f,0.f,0.f,0.f,0.f,0.f,
                           0.f,0.f,0.f,0.f,0.f,0.f,0.f,0.f};

    double Brun[2];
    float  Srun[2];
#pragma unroll
    for (int t = 0; t < 2; ++t) { Brun[t] = dpack(-INFINITY, 0u); Srun[t] = -INFINITY; }

#pragma unroll 1
    for (int pass = 0; pass < 8; ++pass) {
        const int cbase = pass * 128 + wv * 32;
        // ---- A fragments: lane's code row = cbase + px, k = chunk*16 + half8 + j
        const unsigned short* pe = epack + (cbase + px) * 128 + half8;
        const short8 ah0 = *(const short8*)(pe);
        const short8 ah1 = *(const short8*)(pe + 16);
        const short8 ah2 = *(const short8*)(pe + 32);
        const short8 ah3 = *(const short8*)(pe + 48);
        const short8 al0 = *(const short8*)(pe + 64);
        const short8 al1 = *(const short8*)(pe + 80);
        const short8 al2 = *(const short8*)(pe + 96);
        const short8 al3 = *(const short8*)(pe + 112);
        // ---- enorm for the lane's 16 C/D rows: codes cbase+4*hi32+{0..3,8..11,16..19,24..27}
        f32x16 enf;
        {
            const float4 e0 = *(const float4*)(enorm_s + cbase + 4 * hi32);
            const float4 e1 = *(const float4*)(enorm_s + cbase + 4 * hi32 + 8);
            const float4 e2 = *(const float4*)(enorm_s + cbase + 4 * hi32 + 16);
            const float4 e3 = *(const float4*)(enorm_s + cbase + 4 * hi32 + 24);
            enf[0]=e0.x; enf[1]=e0.y; enf[2]=e0.z; enf[3]=e0.w;
            enf[4]=e1.x; enf[5]=e1.y; enf[6]=e1.z; enf[7]=e1.w;
            enf[8]=e2.x; enf[9]=e2.y; enf[10]=e2.z; enf[11]=e2.w;
            enf[12]=e3.x; enf[13]=e3.y; enf[14]=e3.z; enf[15]=e3.w;
        }
        const int K1 = 1023 - cbase - 4 * hi32;

#pragma unroll
        for (int tile = 0; tile < 2; ++tile) {
            const int lpx = tile * 32 + px;
            const int sxp = (lpx & 7) << 3;
            const unsigned short* bp = &afrag[lpx * 128];
            const short8 bh0 = *(const short8*)&bp[(0  + half8) ^ sxp];
            const short8 bh1 = *(const short8*)&bp[(16 + half8) ^ sxp];
            const short8 bh2 = *(const short8*)&bp[(32 + half8) ^ sxp];
            const short8 bh3 = *(const short8*)&bp[(48 + half8) ^ sxp];
            const short8 bl0 = *(const short8*)&bp[64 + ((0  + half8) ^ sxp)];
            const short8 bl1 = *(const short8*)&bp[64 + ((16 + half8) ^ sxp)];
            const short8 bl2 = *(const short8*)&bp[64 + ((32 + half8) ^ sxp)];
            const short8 bl3 = *(const short8*)&bp[64 + ((48 + half8) ^ sxp)];

            // two independent 6-chains: aA = chunks 0,1; aB = chunks 2,3
            f32x16 aA = enf, aB = zero16;
            aA = __builtin_amdgcn_mfma_f32_32x32x16_bf16(ah0, bh0, aA, 0, 0, 0);
            aB = __builtin_amdgcn_mfma_f32_32x32x16_bf16(ah2, bh2, aB, 0, 0, 0);
            aA = __builtin_amdgcn_mfma_f32_32x32x16_bf16(al0, bh0, aA, 0, 0, 0);
            aB = __builtin_amdgcn_mfma_f32_32x32x16_bf16(al2, bh2, aB, 0, 0, 0);
            aA = __builtin_amdgcn_mfma_f32_32x32x16_bf16(ah0, bl0, aA, 0, 0, 0);
            aB = __builtin_amdgcn_mfma_f32_32x32x16_bf16(ah2, bl2, aB, 0, 0, 0);
            aA = __builtin_amdgcn_mfma_f32_32x32x16_bf16(ah1, bh1, aA, 0, 0, 0);
            aB = __builtin_amdgcn_mfma_f32_32x32x16_bf16(ah3, bh3, aB, 0, 0, 0);
            aA = __builtin_amdgcn_mfma_f32_32x32x16_bf16(al1, bh1, aA, 0, 0, 0);
            aB = __builtin_amdgcn_mfma_f32_32x32x16_bf16(al3, bh3, aB, 0, 0, 0);
            aA = __builtin_amdgcn_mfma_f32_32x32x16_bf16(ah1, bl1, aA, 0, 0, 0);
            aB = __builtin_amdgcn_mfma_f32_32x32x16_bf16(ah3, bl3, aB, 0, 0, 0);

            // 16 packed candidates (row reg -> code K1-(reg&3)-8*(reg>>2))
            double cand[16];
#pragma unroll
            for (int reg = 0; reg < 16; ++reg)
                cand[reg] = dpack(aA[reg] + aB[reg],
                                  (unsigned)(K1 - (reg & 3) - 8 * (reg >> 2)));
            // in-register binary tree (B,S) reduce over 16
            double tB[8]; float tS[8];
#pragma unroll
            for (int i = 0; i < 8; ++i) {
                tB[i] = fmax(cand[2 * i], cand[2 * i + 1]);
                tS[i] = fminf(dhi(cand[2 * i]), dhi(cand[2 * i + 1]));
            }
#pragma unroll
            for (int lvl = 4; lvl >= 1; lvl >>= 1) {
#pragma unroll
                for (int i = 0; i < lvl; ++i) {
                    tS[i] = __builtin_amdgcn_fmed3f(dhi(tB[i]), dhi(tB[i + lvl]),
                                                    fmaxf(tS[i], tS[i + lvl]));
                    tB[i] = fmax(tB[i], tB[i + lvl]);
                }
            }
            Srun[tile] = __builtin_amdgcn_fmed3f(dhi(Brun[tile]), dhi(tB[0]),
                                                 fmaxf(Srun[tile], tS[0]));
            Brun[tile] = fmax(Brun[tile], tB[0]);
        }
    }

    // ---- merge code-halves across lane^32 (each tile), select own px slot
#pragma unroll
    for (int t = 0; t < 2; ++t) {
        const double ob = __shfl_xor(Brun[t], 32, 64);
        const float  o2 = __shfl_xor(Srun[t], 32, 64);
        Srun[t] = __builtin_amdgcn_fmed3f(dhi(Brun[t]), dhi(ob), fmaxf(Srun[t], o2));
        Brun[t] = fmax(Brun[t], ob);
    }
    __syncthreads();              // afrag reads complete
    mrgB[wv * 64 + lane] = hi32 ? Brun[1] : Brun[0];   // lane<32: px tile0; else tile1
    mrgS[wv * 64 + lane] = hi32 ? Srun[1] : Srun[0];
    __syncthreads();

    // ---- wave 0: merge the 4 waves' results -> idx + risky compact
    if (tid < 64) {
        double B = mrgB[tid];
        float  S = mrgS[tid];
#pragma unroll
        for (int w = 1; w < 4; ++w) {
            const double ob = mrgB[w * 64 + tid];
            const float  o2 = mrgS[w * 64 + tid];
            S = __builtin_amdgcn_fmed3f(dhi(B), dhi(ob), fmaxf(S, o2));
            B = fmax(B, ob);
        }
        const int idx = 1023 - (int)dlo(B);
        sidx[tid] = idx;
        out[ZQ_ELEMS + 1 + pblk + tid] = (float)idx;
        const bool risk = (dhi(B) - S < EPS_HALF);
        const unsigned long long m = __ballot(risk);
        int base = 0;
        if (lane == 0 && m) base = atomicAdd(risky_cnt, __popcll(m));
        base = __shfl(base, 0, 64);
        if (risk) risky[base + __popcll(m & ((1ull << lane) - 1ull))] = pblk + tid;
    }
    __syncthreads();

    // ---- gather: coalesced codebook-row reads (zq aliases afrag+mrgB)
#pragma unroll
    for (int i = 0; i < 16; ++i) {
        const int p = wv * 16 + i;
        const int k = sidx[p];                 // LDS read, wave-uniform broadcast
        zq[p][lane] = emb[k * 64 + lane];
    }
    __syncthreads();

    // ---- (B,D,H,W)-major float4 writes + fused loss
    const int batch = pblk >> 12;
    const int hw0   = pblk & 4095;
    const int p4 = (tid & 15) * 4;
    const float* zeb = z_e + batch * 262144 + hw0;
    float* ob = out + batch * 262144 + hw0;
    float ss = 0.f;
#pragma unroll
    for (int it = 0; it < 4; ++it) {
        const int d = (tid >> 4) + it * 16;
        float4 q;
        q.x = zq[p4 + 0][d]; q.y = zq[p4 + 1][d];
        q.z = zq[p4 + 2][d]; q.w = zq[p4 + 3][d];
        const float4 z = *(const float4*)(zeb + d * 4096 + p4);
        *(float4*)(ob + d * 4096 + p4) = q;
        const float e0 = q.x - z.x, e1 = q.y - z.y, e2 = q.z - z.z, e3 = q.w - z.w;
        ss += e0 * e0 + e1 * e1 + e2 * e2 + e3 * e3;
    }
    for (int off = 32; off; off >>= 1) ss += __shfl_down(ss, off, 64);
    if (lane == 0) sred[wv] = ss;
    __syncthreads();
    if (tid == 0)
        atomicAdd(out + ZQ_ELEMS,
                  ((sred[0] + sred[1]) + (sred[2] + sred[3])) * (1.25f / (float)ZQ_ELEMS));
}

// Exact fp64 fixup (r18 proven version): wave per flagged pixel; emb staged
// per 64-code tile into padded LDS. Patches idx + z_q row + loss delta.
// Grid 512; idle blocks exit.
__global__ __launch_bounds__(256) void vq_fix(const float* __restrict__ z_e,
        const float* __restrict__ emb, float* __restrict__ out,
        const int* __restrict__ cnt, const int* __restrict__ list) {
    const int n = *cnt;
    if ((int)blockIdx.x * 4 >= n) return;
    __shared__ float etile[64][65];
    const int tid  = threadIdx.x;
    const int lane = tid & 63;
    const int wv   = __builtin_amdgcn_readfirstlane(tid >> 6);

    for (int base = blockIdx.x * 4; base < n; base += gridDim.x * 4) {
        const int item = base + wv;
        const bool active = item < n;
        int pix = 0, oldk = 0;
        float f[64];
        if (active) {
            pix = list[item];
            const float* zb = z_e + (pix >> 12) * 262144 + (pix & 4095);
#pragma unroll
            for (int d = 0; d < 64; ++d) f[d] = zb[d * 4096];
            oldk = (int)out[ZQ_ELEMS + 1 + pix];
        }
        double best = INFINITY; int bk = KC;
        double dold = 0.0;
        for (int j = 0; j < 16; ++j) {
            __syncthreads();
#pragma unroll
            for (int i = 0; i < 16; ++i) {
                const int idx = i * 256 + tid;
                etile[idx >> 6][idx & 63] = emb[j * 4096 + idx];
            }
            __syncthreads();
            if (active) {
                const int k = j * 64 + lane;
                double a0 = 0.0, a1 = 0.0;
#pragma unroll
                for (int d = 0; d < 64; d += 2) {
                    const double d0 = (double)f[d]     - (double)etile[lane][d];
                    const double d1 = (double)f[d + 1] - (double)etile[lane][d + 1];
                    a0 = fma(d0, d0, a0);
                    a1 = fma(d1, d1, a1);
                }
                const double acc = a0 + a1;
                if (acc < best || (acc == best && k < bk)) { best = acc; bk = k; }
                if (k == oldk) dold = acc;
            }
        }
        if (active) {
            for (int off = 32; off; off >>= 1) {
                const double ov = __shfl_down(best, off, 64);
                const int    oi = __shfl_down(bk, off, 64);
                if (ov < best || (ov == best && oi < bk)) { best = ov; bk = oi; }
            }
            for (int off = 32; off; off >>= 1) dold += __shfl_down(dold, off, 64);
            bk   = __shfl(bk, 0, 64);
            best = __shfl(best, 0, 64);
            dold = __shfl(dold, 0, 64);
            if (bk != oldk) {
                if (lane == 0) out[ZQ_ELEMS + 1 + pix] = (float)bk;
                out[(pix >> 12) * 262144 + (pix & 4095) + lane * 4096] = emb[bk * 64 + lane];
                if (lane == 0)
                    atomicAdd(out + ZQ_ELEMS,
                              (float)((best - dold) * (1.25 / (double)ZQ_ELEMS)));
            }
        }
    }
}

extern "C" void kernel_launch(void* const* d_in, const int* in_sizes, int n_in,
                              void* d_out, int out_size, void* d_ws, size_t ws_size,
                              hipStream_t stream) {
    const float* z_e = (const float*)d_in[0];
    const float* emb = (const float*)d_in[1];
    float* out = (float*)d_out;
    char* ws = (char*)d_ws;
    unsigned short* epack = (unsigned short*)ws;
    float*  enorm_s   = (float*)(ws + 262144);
    int*    risky_cnt = (int*)(ws + 266240);
    int*    risky     = (int*)(ws + 270336);

    vq_prep<<<4, 256, 0, stream>>>(emb, epack, enorm_s, risky_cnt, out);
    vq_scan<<<1024, 256, 0, stream>>>(z_e, epack, enorm_s, emb, out, risky_cnt, risky);
    vq_fix<<<512, 256, 0, stream>>>(z_e, emb, out, risky_cnt, risky);
}

// Round 24
// 78.728 us; speedup vs baseline: 1.0233x; 1.0230x over previous
//
#include <hip/hip_runtime.h>
#include <math.h>

typedef short  short8 __attribute__((ext_vector_type(8)));
typedef float  f32x4  __attribute__((ext_vector_type(4)));

#define ZQ_ELEMS 4194304    // 16*64*64*64
#define KC       1024
#define EPS_HALF 0.005f

// Output layout (fp32, concat): [0,4194304) z_q_st ; [4194304] vq_loss ;
// [4194305, 4259841) indices (as float)
//
// ws layout (bytes):
//   [0,262144)           ushort epack[1024][128]   per code: hi[64] | lo[64]
//   [262144,266240)      float  enorm[1024]
//   [266240,266244)      int    risky_cnt
//   [270336,524288)      int    risky[63488]

__device__ inline unsigned short bf16_rne(float f) {
    union { float fv; unsigned u; } a; a.fv = f;
    unsigned r = a.u + 0x7FFFu + ((a.u >> 16) & 1u);
    return (unsigned short)(r >> 16);
}
__device__ inline float bf16_to_f(unsigned short h) {
    union { unsigned u; float fv; } a; a.u = ((unsigned)h) << 16;
    return a.fv;
}
// packed (score, 1023-code) ordered compare via f64 max; near-ties are all
// rescored exactly, so tie direction here is irrelevant.
__device__ inline double dpack(float hi, unsigned lo) {
    return __hiloint2double(__float_as_int(hi), (int)lo);
}
__device__ inline float dhi(double d) { return __int_as_float(__double2hiint(d)); }
__device__ inline unsigned dlo(double d) { return (unsigned)__double2loint(d); }

__global__ __launch_bounds__(256) void vq_prep(const float* __restrict__ emb,
        unsigned short* __restrict__ epack, float* __restrict__ enorm,
        int* __restrict__ risky_cnt, float* __restrict__ out) {
    const int k = blockIdx.x * 256 + threadIdx.x;   // grid 4
    if (k == 0) { *risky_cnt = 0; out[ZQ_ELEMS] = 0.f; }
    const float4* e4 = (const float4*)(emb + k * 64);
    float s = 0.f;
#pragma unroll
    for (int j = 0; j < 16; ++j) {
        float4 v = e4[j];
        float vv[4] = {v.x, v.y, v.z, v.w};
        ushort4 hv, lv;
        unsigned short h[4], l[4];
#pragma unroll
        for (int t = 0; t < 4; ++t) {
            s = fmaf(vv[t], vv[t], s);
            h[t] = bf16_rne(vv[t]);
            l[t] = bf16_rne(vv[t] - bf16_to_f(h[t]));
        }
        hv.x = h[0]; hv.y = h[1]; hv.z = h[2]; hv.w = h[3];
        lv.x = l[0]; lv.y = l[1]; lv.z = l[2]; lv.w = l[3];
        *(ushort4*)(epack + k * 128 + j * 4)      = hv;
        *(ushort4*)(epack + k * 128 + 64 + j * 4) = lv;
    }
    enorm[k] = s;
}

// Block-local full pipeline: block = 64 px x ALL 1024 codes (4 passes of the
// r10 wave geometry: 4 waves x 64 resident codes). Indices finalize in-block;
// gather + z_q write + loss run inline. Grid 1024. No cross-block dataflow.
__global__ __launch_bounds__(256) void vq_scan(const float* __restrict__ z_e,
        const unsigned short* __restrict__ epack, const float* __restrict__ enorm,
        const float* __restrict__ emb, float* __restrict__ out,
        int* __restrict__ risky_cnt, int* __restrict__ risky) {
    const int tid  = threadIdx.x;
    const int lane = tid & 63;
    const int col  = lane & 15;
    const int g    = lane >> 4;
    const int wv   = __builtin_amdgcn_readfirstlane(tid >> 6);
    const int pblk = blockIdx.x * 64;

    __shared__ __align__(16) char smem[19456];
    unsigned short* afrag = (unsigned short*)smem;          // [64 px][hi64|lo64]
    double* mrgB = (double*)(smem + 16384);                 // [4][64]
    float*  mrgS = (float*)(smem + 18432);                  // [4][64]
    float (*zq)[65] = (float (*)[65])smem;                  // gather alias (16.6KB)
    __shared__ int   sidx[64];
    __shared__ float sred[4];

    // ---- stage + convert 64 pixels into LDS (once; no redundancy)
    {
        const int lp = tid & 63;
        const int pg = pblk + lp;
        const float* zb = z_e + (pg >> 12) * 262144 + (pg & 4095);
        const int sx = (lp & 7) << 3;
#pragma unroll
        for (int s8 = 0; s8 < 2; ++s8) {
            const int d0 = wv * 16 + s8 * 8;
            short8 H, L;
#pragma unroll
            for (int j = 0; j < 8; ++j) {
                float v = zb[(d0 + j) * 4096];
                unsigned short h = bf16_rne(v);
                H[j] = (short)h;
                L[j] = (short)bf16_rne(v - bf16_to_f(h));
            }
            const int sw = d0 ^ sx;                // 16B-granular XOR swizzle
            *(short8*)&afrag[lp * 128 + sw]      = H;
            *(short8*)&afrag[lp * 128 + 64 + sw] = L;
        }
    }
    __syncthreads();

    const f32x4 zero4 = {0.f, 0.f, 0.f, 0.f};
    const int g8 = g * 8;

    double Brun[4];
    float  Srun[4];
#pragma unroll
    for (int it = 0; it < 4; ++it) { Brun[it] = dpack(-INFINITY, 0u); Srun[it] = -INFINITY; }

    // ---- 4 passes: wave's 64 resident codes sweep the 64 px (4 it x 16 px)
#pragma unroll 1
    for (int pass = 0; pass < 4; ++pass) {
        const int cbase = pass * 256 + wv * 64;
        short8 ah[4][2], al[4][2];
        f32x4 enf[4];
#pragma unroll
        for (int t = 0; t < 4; ++t) {
            const int code = cbase + t * 16 + col;
            const short8* ph = (const short8*)(epack + code * 128) + g;
            ah[t][0] = ph[0]; ah[t][1] = ph[4];
            al[t][0] = ph[8]; al[t][1] = ph[12];
            const float4 e4 = *(const float4*)(enorm + cbase + t * 16 + g * 4);
            enf[t][0] = -0.5f * e4.x; enf[t][1] = -0.5f * e4.y;
            enf[t][2] = -0.5f * e4.z; enf[t][3] = -0.5f * e4.w;
        }
        const int K1 = 1023 - cbase - g * 4;

#pragma unroll
        for (int it = 0; it < 4; ++it) {
            const int lpx = it * 16 + col;
            const int sxp = (lpx & 7) << 3;
            const unsigned short* ap = &afrag[lpx * 128];
            const short8 bh0 = *(const short8*)&ap[(g8     ) ^ sxp];
            const short8 bh1 = *(const short8*)&ap[(32 + g8) ^ sxp];
            const short8 bl0 = *(const short8*)&ap[64 + ((g8     ) ^ sxp)];
            const short8 bl1 = *(const short8*)&ap[64 + ((32 + g8) ^ sxp)];

            double B = Brun[it];
            float  S = Srun[it];
#pragma unroll
            for (int t = 0; t < 4; ++t) {
                f32x4 aA, aB;   // chunk0 / chunk1 independent 3-chains
                aA = __builtin_amdgcn_mfma_f32_16x16x32_bf16(ah[t][0], bh0, enf[t], 0, 0, 0);
                aB = __builtin_amdgcn_mfma_f32_16x16x32_bf16(ah[t][1], bh1, zero4, 0, 0, 0);
                aA = __builtin_amdgcn_mfma_f32_16x16x32_bf16(al[t][0], bh0, aA, 0, 0, 0);
                aB = __builtin_amdgcn_mfma_f32_16x16x32_bf16(al[t][1], bh1, aB, 0, 0, 0);
                aA = __builtin_amdgcn_mfma_f32_16x16x32_bf16(ah[t][0], bl0, aA, 0, 0, 0);
                aB = __builtin_amdgcn_mfma_f32_16x16x32_bf16(ah[t][1], bl1, aB, 0, 0, 0);
#pragma unroll
                for (int r = 0; r < 4; ++r) {
                    const float v = aA[r] + aB[r]; // score(code=cbase+t*16+g*4+r, px)
                    S = __builtin_amdgcn_fmed3f(dhi(B), S, v);
                    B = fmax(B, dpack(v, (unsigned)(K1 - t * 16 - r)));
                }
            }
            Brun[it] = B;
            Srun[it] = S;
        }
    }

    // ---- deferred reduce over g (lane bits 4-5): 4 independent shfl chains
#pragma unroll
    for (int it = 0; it < 4; ++it) {
        double B = Brun[it];
        float  S = Srun[it];
#pragma unroll
        for (int s = 16; s < 64; s <<= 1) {
            const double ob = __shfl_xor(B, s, 64);
            const float  o2 = __shfl_xor(S, s, 64);
            S = __builtin_amdgcn_fmed3f(dhi(B), dhi(ob), fmaxf(S, o2));
            B = fmax(B, ob);
        }
        Brun[it] = B;
        Srun[it] = S;
    }
    __syncthreads();              // afrag reads complete
    if (g == 0) {
#pragma unroll
        for (int it = 0; it < 4; ++it) {
            mrgB[wv * 64 + it * 16 + col] = Brun[it];
            mrgS[wv * 64 + it * 16 + col] = Srun[it];
        }
    }
    __syncthreads();

    // ---- wave 0: merge the 4 waves' results -> idx + risky compact
    if (tid < 64) {
        double B = mrgB[tid];
        float  S = mrgS[tid];
#pragma unroll
        for (int w = 1; w < 4; ++w) {
            const double ob = mrgB[w * 64 + tid];
            const float  o2 = mrgS[w * 64 + tid];
            S = __builtin_amdgcn_fmed3f(dhi(B), dhi(ob), fmaxf(S, o2));
            B = fmax(B, ob);
        }
        const int idx = 1023 - (int)dlo(B);
        sidx[tid] = idx;
        out[ZQ_ELEMS + 1 + pblk + tid] = (float)idx;
        const bool risk = (dhi(B) - S < EPS_HALF);
        const unsigned long long m = __ballot(risk);
        int base = 0;
        if (lane == 0 && m) base = atomicAdd(risky_cnt, __popcll(m));
        base = __shfl(base, 0, 64);
        if (risk) risky[base + __popcll(m & ((1ull << lane) - 1ull))] = pblk + tid;
    }
    __syncthreads();

    // ---- gather: coalesced codebook-row reads (zq aliases afrag+mrgB)
#pragma unroll
    for (int i = 0; i < 16; ++i) {
        const int p = wv * 16 + i;
        const int k = sidx[p];                 // LDS read, wave-uniform broadcast
        zq[p][lane] = emb[k * 64 + lane];
    }
    __syncthreads();

    // ---- (B,D,H,W)-major float4 writes + fused loss
    const int batch = pblk >> 12;
    const int hw0   = pblk & 4095;
    const int p4 = (tid & 15) * 4;
    const float* zeb = z_e + batch * 262144 + hw0;
    float* ob = out + batch * 262144 + hw0;
    float ss = 0.f;
#pragma unroll
    for (int it = 0; it < 4; ++it) {
        const int d = (tid >> 4) + it * 16;
        float4 q;
        q.x = zq[p4 + 0][d]; q.y = zq[p4 + 1][d];
        q.z = zq[p4 + 2][d]; q.w = zq[p4 + 3][d];
        const float4 z = *(const float4*)(zeb + d * 4096 + p4);
        *(float4*)(ob + d * 4096 + p4) = q;
        const float e0 = q.x - z.x, e1 = q.y - z.y, e2 = q.z - z.z, e3 = q.w - z.w;
        ss += e0 * e0 + e1 * e1 + e2 * e2 + e3 * e3;
    }
    for (int off = 32; off; off >>= 1) ss += __shfl_down(ss, off, 64);
    if (lane == 0) sred[wv] = ss;
    __syncthreads();
    if (tid == 0)
        atomicAdd(out + ZQ_ELEMS,
                  ((sred[0] + sred[1]) + (sred[2] + sred[3])) * (1.25f / (float)ZQ_ELEMS));
}

// Exact fp64 fixup: wave per flagged pixel; emb staged per 64-code tile into
// padded LDS. Patches idx + z_q row + loss delta. Grid 512; idle blocks exit.
__global__ __launch_bounds__(256) void vq_fix(const float* __restrict__ z_e,
        const float* __restrict__ emb, float* __restrict__ out,
        const int* __restrict__ cnt, const int* __restrict__ list) {
    const int n = *cnt;
    if ((int)blockIdx.x * 4 >= n) return;
    __shared__ float etile[64][65];
    const int tid  = threadIdx.x;
    const int lane = tid & 63;
    const int wv   = __builtin_amdgcn_readfirstlane(tid >> 6);

    for (int base = blockIdx.x * 4; base < n; base += gridDim.x * 4) {
        const int item = base + wv;
        const bool active = item < n;
        int pix = 0, oldk = 0;
        float f[64];
        if (active) {
            pix = list[item];
            const float* zb = z_e + (pix >> 12) * 262144 + (pix & 4095);
#pragma unroll
            for (int d = 0; d < 64; ++d) f[d] = zb[d * 4096];
            oldk = (int)out[ZQ_ELEMS + 1 + pix];
        }
        double best = INFINITY; int bk = KC;
        double dold = 0.0;
        for (int j = 0; j < 16; ++j) {
            __syncthreads();
#pragma unroll
            for (int i = 0; i < 16; ++i) {
                const int idx = i * 256 + tid;
                etile[idx >> 6][idx & 63] = emb[j * 4096 + idx];
            }
            __syncthreads();
            if (active) {
                const int k = j * 64 + lane;
                double a0 = 0.0, a1 = 0.0;
#pragma unroll
                for (int d = 0; d < 64; d += 2) {
                    const double d0 = (double)f[d]     - (double)etile[lane][d];
                    const double d1 = (double)f[d + 1] - (double)etile[lane][d + 1];
                    a0 = fma(d0, d0, a0);
                    a1 = fma(d1, d1, a1);
                }
                const double acc = a0 + a1;
                if (acc < best || (acc == best && k < bk)) { best = acc; bk = k; }
                if (k == oldk) dold = acc;
            }
        }
        if (active) {
            for (int off = 32; off; off >>= 1) {
                const double ov = __shfl_down(best, off, 64);
                const int    oi = __shfl_down(bk, off, 64);
                if (ov < best || (ov == best && oi < bk)) { best = ov; bk = oi; }
            }
            for (int off = 32; off; off >>= 1) dold += __shfl_down(dold, off, 64);
            bk   = __shfl(bk, 0, 64);
            best = __shfl(best, 0, 64);
            dold = __shfl(dold, 0, 64);
            if (bk != oldk) {
                if (lane == 0) out[ZQ_ELEMS + 1 + pix] = (float)bk;
                out[(pix >> 12) * 262144 + (pix & 4095) + lane * 4096] = emb[bk * 64 + lane];
                if (lane == 0)
                    atomicAdd(out + ZQ_ELEMS,
                              (float)((best - dold) * (1.25 / (double)ZQ_ELEMS)));
            }
        }
    }
}

extern "C" void kernel_launch(void* const* d_in, const int* in_sizes, int n_in,
                              void* d_out, int out_size, void* d_ws, size_t ws_size,
                              hipStream_t stream) {
    const float* z_e = (const float*)d_in[0];
    const float* emb = (const float*)d_in[1];
    float* out = (float*)d_out;
    char* ws = (char*)d_ws;
    unsigned short* epack = (unsigned short*)ws;
    float*  enorm     = (float*)(ws + 262144);
    int*    risky_cnt = (int*)(ws + 266240);
    int*    risky     = (int*)(ws + 270336);

    vq_prep<<<4, 256, 0, stream>>>(emb, epack, enorm, risky_cnt, out);
    vq_scan<<<1024, 256, 0, stream>>>(z_e, epack, enorm, emb, out, risky_cnt, risky);
    vq_fix<<<512, 256, 0, stream>>>(z_e, emb, out, risky_cnt, risky);
}